// Round 12
// baseline (609.533 us; speedup 1.0000x reference)
//
#include <hip/hip_runtime.h>

#define N_NODES 100000
#define N_EDGES 1600000
#define D 64
#define PN 256                       // nodes per partition
#define P 391                        // ceil(N_NODES / PN); last partition has 160 nodes
#define BCAP 24                      // LDS bin capacity per partition (flush at >=16)
#define ACAP 4864                    // global area slots per partition (mean 4096, +12 sigma, %16==0)
#define OVF_CAP 8192                 // overflow list entries
#define NT 2048                      // transform blocks in K1
#define NBB 32                       // bin blocks in K1
#define EPB1 (N_EDGES / NBB)         // 50000 edges per bin block
#define CAPL 56                      // per-node LDS list slots in K2 (Poisson(16): P(>56) ~ 1e-16)

// round-to-nearest-even f32 -> bf16
static __device__ inline unsigned short f2bf(float f) {
    unsigned u = __float_as_uint(f);
    return (unsigned short)((u + 0x7fffu + ((u >> 16) & 1u)) >> 16);
}
static __device__ inline float bflo(unsigned u) { return __uint_as_float(u << 16); }
static __device__ inline float bfhi(unsigned u) { return __uint_as_float(u & 0xffff0000u); }
static __device__ inline float bf2f(unsigned short v) { return __uint_as_float(((unsigned)v) << 16); }

// ---------- fallback path (verified round 2; only if ws too small) ----------
__global__ __launch_bounds__(256) void init_kernel(const float* __restrict__ b,
                                                   float* __restrict__ out) {
    int idx = blockIdx.x * blockDim.x + threadIdx.x;
    int total4 = N_NODES * D / 4;
    if (idx < total4) {
        int col4 = idx & (D / 4 - 1);
        ((float4*)out)[idx] = ((const float4*)b)[col4];
    }
}

__global__ __launch_bounds__(256) void scatter_kernel(const int* __restrict__ src,
                                                      const int* __restrict__ dst,
                                                      const float* __restrict__ g,
                                                      float* __restrict__ out) {
    long long t = (long long)blockIdx.x * blockDim.x + threadIdx.x;
    int e = (int)(t >> 6);
    int lane = (int)(t & 63);
    if (e < N_EDGES) {
        int s = src[e];
        int d = dst[e];
        float v = g[(size_t)s * D + lane];
        atomicAdd(&out[(size_t)d * D + lane], v);
    }
}

__global__ __launch_bounds__(256) void transform_fallback(const float* __restrict__ feature,
                                                          const float* __restrict__ W,
                                                          float* __restrict__ g) {
    __shared__ float ldsWT[D * (D + 1)];
    int tid = threadIdx.x;
    for (int i = tid; i < D * D; i += 256) {
        int j = i >> 6, k = i & 63;
        ldsWT[k * (D + 1) + j] = W[i];
    }
    __syncthreads();
    int r = tid >> 6, lane = tid & 63;
    for (int row = blockIdx.x * 4 + r; row < N_NODES; row += 4 * 2048) {
        float f = feature[(size_t)row * D + lane];
        float acc = 0.f;
        #pragma unroll
        for (int k = 0; k < D; ++k)
            acc += __shfl(f, k, 64) * ldsWT[k * (D + 1) + lane];
        g[(size_t)row * D + lane] = acc;
    }
}

// ---------- K1: transform (gbf = bf16(feature @ W^T)) + LDS-binned partition sort ----
// R2/R7/R8/R11 lock-in: scattered 4B global stores cost ~60B writeback each,
// unconditionally. So edges are staged in per-partition LDS bins and flushed as
// 16-entry contiguous runs from one thread (back-to-back dword stores to one
// 64B-aligned-ish run -> L2 merges -> full-line writeback). Entry = (src<<8)|dstLocal.
__global__ __launch_bounds__(256) void k1_kernel(const float* __restrict__ feature,
                                                 const float* __restrict__ W,
                                                 unsigned short* __restrict__ gbf,
                                                 const int* __restrict__ src,
                                                 const int* __restrict__ dst,
                                                 int* __restrict__ gcount,
                                                 unsigned* __restrict__ binArea,
                                                 int* __restrict__ ovfCnt,
                                                 uint2* __restrict__ ovf) {
    __shared__ __align__(16) char smem[39168];   // bin: 1600 + 37536 / transform: 20480

    int idx = blockIdx.x;                        // grid = 2080; every 65th block bins
    int tid = threadIdx.x;
    bool is_bin = (idx % 65) == 0;

    if (is_bin) {
        int* lcount    = (int*)smem;             // 391 (padded to 400)
        unsigned* lbin = (unsigned*)(smem + 1600);   // 391 * BCAP
        int id = idx / 65;                       // 0..31
        int lo = id * EPB1, hi = lo + EPB1;

        for (int i = tid; i < P; i += 256) lcount[i] = 0;
        __syncthreads();

        for (int base = lo; base < hi; base += 256) {
            int i = base + tid;
            if (i < hi) {
                int d = dst[i];
                int s = src[i];
                int p = d >> 8;
                unsigned val = ((unsigned)s << 8) | (unsigned)(d & 255);
                int pos = atomicAdd(&lcount[p], 1);
                if (pos < BCAP) lbin[p * BCAP + pos] = val;
                else {                           // extremely rare batch spike
                    int gp = atomicAdd(ovfCnt, 1);
                    if (gp < OVF_CAP) ovf[gp] = make_uint2((unsigned)s, (unsigned)d);
                }
            }
            __syncthreads();
            // flush bins holding >=16 entries as contiguous 16-dword runs
            for (int pb = tid; pb < P; pb += 256) {
                int c = lcount[pb]; if (c > BCAP) c = BCAP;
                while (c >= 16) {
                    int gb = atomicAdd(&gcount[pb], 16);
                    unsigned* dp = &binArea[(size_t)pb * ACAP + gb];
                    #pragma unroll
                    for (int k = 0; k < 16; ++k) {
                        unsigned v = lbin[pb * BCAP + c - 16 + k];
                        if (gb + k < ACAP) dp[k] = v;
                        else {
                            int gp = atomicAdd(ovfCnt, 1);
                            if (gp < OVF_CAP)
                                ovf[gp] = make_uint2(v >> 8, (unsigned)(pb * PN) + (v & 255u));
                        }
                    }
                    c -= 16;
                }
                lcount[pb] = c;
            }
            __syncthreads();
        }
        // residual flush (0..15 entries per bin)
        for (int pb = tid; pb < P; pb += 256) {
            int c = lcount[pb]; if (c > BCAP) c = BCAP;
            if (c > 0) {
                int gb = atomicAdd(&gcount[pb], c);
                for (int k = 0; k < c; ++k) {
                    unsigned v = lbin[pb * BCAP + k];
                    if (gb + k < ACAP) binArea[(size_t)pb * ACAP + gb + k] = v;
                    else {
                        int gp = atomicAdd(ovfCnt, 1);
                        if (gp < OVF_CAP)
                            ovf[gp] = make_uint2(v >> 8, (unsigned)(pb * PN) + (v & 255u));
                    }
                }
            }
        }
        return;
    }

    // ---- transform block: id 0..2047 (R7-verified math, plain loads) ----
    float4* ldsW = (float4*)smem;                // 16 KB, XOR-swizzled
    float4* ldsF = (float4*)(smem + 16384);      // 4 KB
    int id = idx - idx / 65 - 1;
    {
        const float4* W4 = (const float4*)W;
        #pragma unroll
        for (int t = 0; t < 4; ++t) {
            int i = tid + t * 256;
            int j = i >> 4, k4 = i & 15;
            ldsW[j * 16 + (k4 ^ (j & 15))] = W4[i];
        }
    }
    int wave = tid >> 6, lane = tid & 63;
    int r0 = wave * 4;
    int lx = lane & 15;

    for (int base = id * 16; base < N_NODES; base += NT * 16) {
        __syncthreads();
        ldsF[tid] = ((const float4*)(feature + (size_t)base * D))[tid];
        __syncthreads();

        float a0 = 0.f, a1 = 0.f, a2 = 0.f, a3 = 0.f;
        #pragma unroll
        for (int t = 0; t < 16; ++t) {
            float4 w  = ldsW[lane * 16 + (t ^ lx)];
            float4 f0 = ldsF[(r0 + 0) * 16 + t];
            float4 f1 = ldsF[(r0 + 1) * 16 + t];
            float4 f2 = ldsF[(r0 + 2) * 16 + t];
            float4 f3 = ldsF[(r0 + 3) * 16 + t];
            a0 += w.x * f0.x + w.y * f0.y + w.z * f0.z + w.w * f0.w;
            a1 += w.x * f1.x + w.y * f1.y + w.z * f1.z + w.w * f1.w;
            a2 += w.x * f2.x + w.y * f2.y + w.z * f2.z + w.w * f2.w;
            a3 += w.x * f3.x + w.y * f3.y + w.z * f3.z + w.w * f3.w;
        }
        size_t o = (size_t)(base + r0) * D + lane;
        gbf[o]         = f2bf(a0);
        gbf[o + D]     = f2bf(a1);
        gbf[o + 2 * D] = f2bf(a2);
        gbf[o + 3 * D] = f2bf(a3);
    }
}

// ---------- K2: one block per partition — LDS list build + R7-style gather ----------
// Sequential read of the partition's entries; per-node lists via LDS *int* atomics
// (cheap, ~4K/block; never f32 — R9 lesson); gather is register-accumulate.
__global__ __launch_bounds__(1024) void k2_kernel(const int* __restrict__ gcount,
                                                  const unsigned* __restrict__ binArea,
                                                  const unsigned short* __restrict__ gbf,
                                                  const float* __restrict__ b,
                                                  float* __restrict__ out,
                                                  int* __restrict__ ovfCnt,
                                                  uint2* __restrict__ ovf) {
    __shared__ int lcur[PN];                     // 1 KB
    __shared__ int lists[PN * CAPL];             // 57.3 KB

    int p = blockIdx.x;
    int tid = threadIdx.x;
    if (tid < PN) lcur[tid] = 0;
    __syncthreads();

    int count = gcount[p];
    if (count > ACAP) count = ACAP;
    const unsigned* area = &binArea[(size_t)p * ACAP];

    for (int i = tid; i < count; i += 1024) {
        unsigned e = area[i];
        int dl = e & 255u;
        int s  = (int)(e >> 8);
        int pos = atomicAdd(&lcur[dl], 1);
        if (pos < CAPL) lists[dl * CAPL + pos] = s;
        else {
            int gp = atomicAdd(ovfCnt, 1);
            if (gp < OVF_CAP) ovf[gp] = make_uint2((unsigned)s, (unsigned)(p * PN + dl));
        }
    }
    __syncthreads();

    int wave = tid >> 6, lane = tid & 63;
    int group = lane >> 3, sub = lane & 7;
    const uint4* g16 = (const uint4*)gbf;        // bf16 row = 8 uint4

    for (int dl = wave; dl < PN; dl += 16) {
        int node = p * PN + dl;
        if (node >= N_NODES) continue;
        int deg = lcur[dl]; if (deg > CAPL) deg = CAPL;
        int s_lane = (lane < deg) ? lists[dl * CAPL + lane] : 0;

        float a[8] = {0.f, 0.f, 0.f, 0.f, 0.f, 0.f, 0.f, 0.f};
        int i = 0;
        for (; i + 16 <= deg; i += 16) {
            int sA = __shfl(s_lane, i + group, 64);
            int sB = __shfl(s_lane, i + 8 + group, 64);
            uint4 vA = g16[(size_t)sA * 8 + sub];
            uint4 vB = g16[(size_t)sB * 8 + sub];
            a[0] += bflo(vA.x) + bflo(vB.x); a[1] += bfhi(vA.x) + bfhi(vB.x);
            a[2] += bflo(vA.y) + bflo(vB.y); a[3] += bfhi(vA.y) + bfhi(vB.y);
            a[4] += bflo(vA.z) + bflo(vB.z); a[5] += bfhi(vA.z) + bfhi(vB.z);
            a[6] += bflo(vA.w) + bflo(vB.w); a[7] += bfhi(vA.w) + bfhi(vB.w);
        }
        for (; i + 8 <= deg; i += 8) {
            int s = __shfl(s_lane, i + group, 64);
            uint4 v = g16[(size_t)s * 8 + sub];
            a[0] += bflo(v.x); a[1] += bfhi(v.x);
            a[2] += bflo(v.y); a[3] += bfhi(v.y);
            a[4] += bflo(v.z); a[5] += bfhi(v.z);
            a[6] += bflo(v.w); a[7] += bfhi(v.w);
        }
        if (i < deg) {
            int n = i + group;
            int s = __shfl(s_lane, n < deg ? n : 0, 64);
            float m = (n < deg) ? 1.f : 0.f;
            uint4 v = g16[(size_t)s * 8 + sub];
            a[0] += m * bflo(v.x); a[1] += m * bfhi(v.x);
            a[2] += m * bflo(v.y); a[3] += m * bfhi(v.y);
            a[4] += m * bflo(v.z); a[5] += m * bfhi(v.z);
            a[6] += m * bflo(v.w); a[7] += m * bfhi(v.w);
        }

        #pragma unroll
        for (int d = 8; d < 64; d <<= 1) {
            #pragma unroll
            for (int jj = 0; jj < 8; ++jj) a[jj] += __shfl_xor(a[jj], d, 64);
        }

        if (lane < 8) {
            const float4* b4 = (const float4*)b;
            float4 b0 = b4[lane * 2], b1 = b4[lane * 2 + 1];
            float4 o0 = make_float4(a[0] + b0.x, a[1] + b0.y, a[2] + b0.z, a[3] + b0.w);
            float4 o1 = make_float4(a[4] + b1.x, a[5] + b1.y, a[6] + b1.z, a[7] + b1.w);
            float4* out4 = (float4*)out;
            out4[(size_t)node * 16 + lane * 2]     = o0;
            out4[(size_t)node * 16 + lane * 2 + 1] = o1;
        }
    }
}

// ---------- K3: overflow fixup (n ~ 0 in practice; correctness backstop) ----------
__global__ __launch_bounds__(256) void k3_kernel(const int* __restrict__ ovfCnt,
                                                 const uint2* __restrict__ ovf,
                                                 const unsigned short* __restrict__ gbf,
                                                 float* __restrict__ out) {
    int n = *ovfCnt; if (n > OVF_CAP) n = OVF_CAP;
    int lane = threadIdx.x & 63;
    for (int i = (int)(threadIdx.x >> 6); i < n; i += 4) {
        uint2 e = ovf[i];
        atomicAdd(&out[(size_t)e.y * D + lane], bf2f(gbf[(size_t)e.x * D + lane]));
    }
}

extern "C" void kernel_launch(void* const* d_in, const int* in_sizes, int n_in,
                              void* d_out, int out_size, void* d_ws, size_t ws_size,
                              hipStream_t stream) {
    const float* feature = (const float*)d_in[0];
    const int*   src     = (const int*)d_in[1];
    const int*   dst     = (const int*)d_in[2];
    const float* W       = (const float*)d_in[3];
    const float* b       = (const float*)d_in[4];
    float* out = (float*)d_out;

    // workspace layout
    size_t gbf_bytes  = (size_t)N_NODES * D * sizeof(unsigned short);   // 12.8 MB
    size_t meta_bytes = 2048;                                           // gcount[391] + ovfCnt
    size_t bin_bytes  = (size_t)P * ACAP * sizeof(unsigned);            // 7.6 MB
    size_t ovf_bytes  = (size_t)OVF_CAP * sizeof(uint2);                // 64 KB
    size_t needed = gbf_bytes + meta_bytes + bin_bytes + ovf_bytes;

    if (ws_size >= needed) {
        unsigned short* gbf = (unsigned short*)d_ws;
        int* meta        = (int*)((char*)d_ws + gbf_bytes);
        int* gcount      = meta;                 // meta[0..390]
        int* ovfCnt      = meta + 400;           // inside the 2048B memset window
        unsigned* binArea = (unsigned*)((char*)d_ws + gbf_bytes + meta_bytes);
        uint2* ovf       = (uint2*)((char*)d_ws + gbf_bytes + meta_bytes + bin_bytes);

        (void)hipMemsetAsync(meta, 0, meta_bytes, stream);
        k1_kernel<<<NT + NBB, 256, 0, stream>>>(feature, W, gbf, src, dst,
                                                gcount, binArea, ovfCnt, ovf);
        k2_kernel<<<P, 1024, 0, stream>>>(gcount, binArea, gbf, b, out, ovfCnt, ovf);
        k3_kernel<<<1, 256, 0, stream>>>(ovfCnt, ovf, gbf, out);
    } else {
        float* g = (float*)d_ws;   // fp32 fallback (verified round 2)
        transform_fallback<<<2048, 256, 0, stream>>>(feature, W, g);
        init_kernel<<<(N_NODES * D / 4 + 255) / 256, 256, 0, stream>>>(b, out);
        long long threads = (long long)N_EDGES * 64;
        scatter_kernel<<<(int)((threads + 255) / 256), 256, 0, stream>>>(src, dst, g, out);
    }
}